// Round 1
// baseline (567.233 us; speedup 1.0000x reference)
//
#include <hip/hip_runtime.h>

namespace {

constexpr int kH = 512, kW = 512, kB = 16, kC = 8;
constexpr int kHW = kH * kW;      // 262144 per-channel plane
constexpr int kBS = kC * kHW;     // 2097152 per-batch stride
constexpr int TW = 64, TH = 4;    // pixel tile per 256-thread block
constexpr int TWP = TW + 2, THP = TH + 2;

// Kernel 1: count alive cells (x[:,3,:,:] > 0.1) over the whole tensor.
__global__ void alive_count_kernel(const float* __restrict__ x, int* __restrict__ cnt) {
    const int total = kB * kHW;  // 4194304
    int idx = blockIdx.x * blockDim.x + threadIdx.x;
    int stride = gridDim.x * blockDim.x;
    int local = 0;
    for (int i = idx; i < total; i += stride) {
        int b = i >> 18;             // kHW == 2^18
        int off = i & (kHW - 1);
        local += (x[b * kBS + 3 * kHW + off] > 0.1f) ? 1 : 0;
    }
    // wave-64 shuffle reduction, one atomic per wave
    for (int off = 32; off > 0; off >>= 1)
        local += __shfl_down(local, off, 64);
    if ((threadIdx.x & 63) == 0) atomicAdd(cnt, local);
}

// Kernel 2: fully fused NCA step.
__global__ __launch_bounds__(256)
void nca_fused_kernel(const float* __restrict__ x,
                      const float* __restrict__ w1, const float* __restrict__ b1,
                      const float* __restrict__ w2, const float* __restrict__ b2,
                      const float* __restrict__ w3, const float* __restrict__ b3,
                      const float* __restrict__ growth,
                      const int* __restrict__ alive_cnt,
                      float* __restrict__ out) {
    // [channel][row][col] tile with 1-pixel halo; row stride 66 floats:
    // wave reads are stride-1 within a row -> 2-way bank aliasing (free).
    __shared__ float tile[kC][THP][TWP];  // 3168 floats = 12672 B

    const int w0 = blockIdx.x * TW;
    const int h0 = blockIdx.y * TH;
    const int b  = blockIdx.z;
    const int tid = threadIdx.x;
    const float* xb = x + b * kBS;

    // ---- stage tile + halo (zero-pad outside the image, matches SAME conv) ----
    constexpr int TILE_N = kC * THP * TWP;  // 3168
    for (int i = tid; i < TILE_N; i += 256) {
        int c  = i / (THP * TWP);
        int r  = i - c * (THP * TWP);
        int hh = r / TWP;
        int ww = r - hh * TWP;
        int gh = h0 + hh - 1;
        int gw = w0 + ww - 1;
        float v = 0.0f;
        if ((unsigned)gh < (unsigned)kH && (unsigned)gw < (unsigned)kW)
            v = xb[c * kHW + gh * kW + gw];
        (&tile[0][0][0])[i] = v;
    }
    __syncthreads();

    const int ww = tid & (TW - 1);
    const int hh = tid >> 6;

    // ---- perceive: [x, sobel_x, sobel_y] (cross-correlation, zero pad) ----
    float p[24];
    int nalive = 0;
#pragma unroll
    for (int c = 0; c < kC; ++c) {
        float a00 = tile[c][hh    ][ww], a01 = tile[c][hh    ][ww + 1], a02 = tile[c][hh    ][ww + 2];
        float a10 = tile[c][hh + 1][ww], a11 = tile[c][hh + 1][ww + 1], a12 = tile[c][hh + 1][ww + 2];
        float a20 = tile[c][hh + 2][ww], a21 = tile[c][hh + 2][ww + 1], a22 = tile[c][hh + 2][ww + 2];
        p[c]      = a11;
        p[8 + c]  = (a02 - a00) + 2.0f * (a12 - a10) + (a22 - a20);   // sobel_x
        p[16 + c] = (a20 - a00) + 2.0f * (a21 - a01) + (a22 - a02);   // sobel_y
        if (c == 3) {
            // 3x3 alive neighborhood (count_include_pad: halo zeros are "dead")
            nalive = (a00 > 0.1f) + (a01 > 0.1f) + (a02 > 0.1f)
                   + (a10 > 0.1f) + (a11 > 0.1f) + (a12 > 0.1f)
                   + (a20 > 0.1f) + (a21 > 0.1f) + (a22 > 0.1f);
        }
    }

    // ---- per-pixel MLP; weight indices are wave-uniform -> scalar loads ----
    float h1[32];
#pragma unroll
    for (int o = 0; o < 32; ++o) {
        float acc = b1[o];
#pragma unroll
        for (int i2 = 0; i2 < 24; ++i2) acc = fmaf(w1[o * 24 + i2], p[i2], acc);
        h1[o] = fmaxf(acc, 0.0f);
    }
    float h2[32];
#pragma unroll
    for (int o = 0; o < 32; ++o) {
        float acc = b2[o];
#pragma unroll
        for (int i2 = 0; i2 < 32; ++i2) acc = fmaf(w2[o * 32 + i2], h1[i2], acc);
        h2[o] = fmaxf(acc, 0.0f);
    }
    float d[8];
#pragma unroll
    for (int o = 0; o < 8; ++o) {
        float acc = b3[o];
#pragma unroll
        for (int i2 = 0; i2 < 32; ++i2) acc = fmaf(w3[o * 32 + i2], h2[i2], acc);
        d[o] = acc;
    }

    // ---- growth boost + clip epilogue ----
    const float g = growth[0];  // GROWTH_BOOST == 1.0
    const float ratio = (float)(*alive_cnt) * (1.0f / 4194304.0f);
    const float boost = (ratio < 0.2f && nalive > 0) ? 0.2f : 0.0f;

    float* ob = out + b * kBS + (h0 + hh) * kW + (w0 + ww);
#pragma unroll
    for (int c = 0; c < kC; ++c) {
        float v = p[c] + d[c] * g + ((c == 3) ? boost : 0.0f);
        // clip(x+dx, -1, 1); then alpha channel additionally clipped to [0,1]
        const float lo = (c == 3) ? 0.0f : -1.0f;
        v = fminf(fmaxf(v, lo), 1.0f);
        ob[c * kHW] = v;
    }
}

}  // namespace

extern "C" void kernel_launch(void* const* d_in, const int* in_sizes, int n_in,
                              void* d_out, int out_size, void* d_ws, size_t ws_size,
                              hipStream_t stream) {
    const float* x  = (const float*)d_in[0];
    const float* w1 = (const float*)d_in[1];
    const float* b1 = (const float*)d_in[2];
    const float* w2 = (const float*)d_in[3];
    const float* b2 = (const float*)d_in[4];
    const float* w3 = (const float*)d_in[5];
    const float* b3 = (const float*)d_in[6];
    const float* gr = (const float*)d_in[7];
    float* out = (float*)d_out;
    int* cnt = (int*)d_ws;  // ws is re-poisoned 0xAA each launch -> must zero

    hipMemsetAsync(cnt, 0, sizeof(int), stream);
    alive_count_kernel<<<2048, 256, 0, stream>>>(x, cnt);
    dim3 grid(kW / TW, kH / TH, kB);
    nca_fused_kernel<<<grid, 256, 0, stream>>>(x, w1, b1, w2, b2, w3, b3, gr, cnt, out);
}

// Round 2
// 476.510 us; speedup vs baseline: 1.1904x; 1.1904x over previous
//
#include <hip/hip_runtime.h>

namespace {

constexpr int kH = 512, kW = 512, kB = 16, kC = 8;
constexpr int kHW = kH * kW;      // 262144 per-channel plane
constexpr int kBS = kC * kHW;     // 2097152 per-batch stride
constexpr int TW = 64, TH = 4;    // pixel tile per 256-thread block
constexpr int TWP = TW + 2, THP = TH + 2;

// Kernel 1: count alive cells (x[:,3,:,:] > 0.1).
// R2 fix: float4 loads, 256 blocks, block-level LDS reduction -> ONE atomic
// per block (256 total vs 8192 same-address atomics in R1, which serialized
// at L2 for ~246 us).
__global__ __launch_bounds__(256)
void alive_count_kernel(const float* __restrict__ x, int* __restrict__ cnt) {
    __shared__ int sdata[4];
    const int tid = threadIdx.x;
    const int total4 = kB * kHW / 4;          // 1048576 float4s across 16 planes
    int idx = blockIdx.x * 256 + tid;
    const int stride = gridDim.x * 256;
    int local = 0;
    const float4* x4 = (const float4*)x;
    for (int i = idx; i < total4; i += stride) {
        int b = i >> 16;                       // kHW/4 == 65536
        int off = i & 65535;
        float4 v = x4[(size_t)b * (kBS / 4) + (3 * kHW / 4) + off];
        local += (v.x > 0.1f) + (v.y > 0.1f) + (v.z > 0.1f) + (v.w > 0.1f);
    }
    // wave-64 shuffle reduction
    for (int off = 32; off > 0; off >>= 1)
        local += __shfl_down(local, off, 64);
    if ((tid & 63) == 0) sdata[tid >> 6] = local;
    __syncthreads();
    if (tid == 0) atomicAdd(cnt, sdata[0] + sdata[1] + sdata[2] + sdata[3]);
}

// Kernel 2: fully fused NCA step (unchanged from R1 — 321 us, VALUBusy 96%).
__global__ __launch_bounds__(256)
void nca_fused_kernel(const float* __restrict__ x,
                      const float* __restrict__ w1, const float* __restrict__ b1,
                      const float* __restrict__ w2, const float* __restrict__ b2,
                      const float* __restrict__ w3, const float* __restrict__ b3,
                      const float* __restrict__ growth,
                      const int* __restrict__ alive_cnt,
                      float* __restrict__ out) {
    __shared__ float tile[kC][THP][TWP];  // 3168 floats = 12672 B

    const int w0 = blockIdx.x * TW;
    const int h0 = blockIdx.y * TH;
    const int b  = blockIdx.z;
    const int tid = threadIdx.x;
    const float* xb = x + b * kBS;

    constexpr int TILE_N = kC * THP * TWP;  // 3168
    for (int i = tid; i < TILE_N; i += 256) {
        int c  = i / (THP * TWP);
        int r  = i - c * (THP * TWP);
        int hh = r / TWP;
        int ww = r - hh * TWP;
        int gh = h0 + hh - 1;
        int gw = w0 + ww - 1;
        float v = 0.0f;
        if ((unsigned)gh < (unsigned)kH && (unsigned)gw < (unsigned)kW)
            v = xb[c * kHW + gh * kW + gw];
        (&tile[0][0][0])[i] = v;
    }
    __syncthreads();

    const int ww = tid & (TW - 1);
    const int hh = tid >> 6;

    float p[24];
    int nalive = 0;
#pragma unroll
    for (int c = 0; c < kC; ++c) {
        float a00 = tile[c][hh    ][ww], a01 = tile[c][hh    ][ww + 1], a02 = tile[c][hh    ][ww + 2];
        float a10 = tile[c][hh + 1][ww], a11 = tile[c][hh + 1][ww + 1], a12 = tile[c][hh + 1][ww + 2];
        float a20 = tile[c][hh + 2][ww], a21 = tile[c][hh + 2][ww + 1], a22 = tile[c][hh + 2][ww + 2];
        p[c]      = a11;
        p[8 + c]  = (a02 - a00) + 2.0f * (a12 - a10) + (a22 - a20);   // sobel_x
        p[16 + c] = (a20 - a00) + 2.0f * (a21 - a01) + (a22 - a02);   // sobel_y
        if (c == 3) {
            nalive = (a00 > 0.1f) + (a01 > 0.1f) + (a02 > 0.1f)
                   + (a10 > 0.1f) + (a11 > 0.1f) + (a12 > 0.1f)
                   + (a20 > 0.1f) + (a21 > 0.1f) + (a22 > 0.1f);
        }
    }

    float h1[32];
#pragma unroll
    for (int o = 0; o < 32; ++o) {
        float acc = b1[o];
#pragma unroll
        for (int i2 = 0; i2 < 24; ++i2) acc = fmaf(w1[o * 24 + i2], p[i2], acc);
        h1[o] = fmaxf(acc, 0.0f);
    }
    float h2[32];
#pragma unroll
    for (int o = 0; o < 32; ++o) {
        float acc = b2[o];
#pragma unroll
        for (int i2 = 0; i2 < 32; ++i2) acc = fmaf(w2[o * 32 + i2], h1[i2], acc);
        h2[o] = fmaxf(acc, 0.0f);
    }
    float d[8];
#pragma unroll
    for (int o = 0; o < 8; ++o) {
        float acc = b3[o];
#pragma unroll
        for (int i2 = 0; i2 < 32; ++i2) acc = fmaf(w3[o * 32 + i2], h2[i2], acc);
        d[o] = acc;
    }

    const float g = growth[0];  // GROWTH_BOOST == 1.0
    const float ratio = (float)(*alive_cnt) * (1.0f / 4194304.0f);
    const float boost = (ratio < 0.2f && nalive > 0) ? 0.2f : 0.0f;

    float* ob = out + b * kBS + (h0 + hh) * kW + (w0 + ww);
#pragma unroll
    for (int c = 0; c < kC; ++c) {
        float v = p[c] + d[c] * g + ((c == 3) ? boost : 0.0f);
        const float lo = (c == 3) ? 0.0f : -1.0f;
        v = fminf(fmaxf(v, lo), 1.0f);
        ob[c * kHW] = v;
    }
}

}  // namespace

extern "C" void kernel_launch(void* const* d_in, const int* in_sizes, int n_in,
                              void* d_out, int out_size, void* d_ws, size_t ws_size,
                              hipStream_t stream) {
    const float* x  = (const float*)d_in[0];
    const float* w1 = (const float*)d_in[1];
    const float* b1 = (const float*)d_in[2];
    const float* w2 = (const float*)d_in[3];
    const float* b2 = (const float*)d_in[4];
    const float* w3 = (const float*)d_in[5];
    const float* b3 = (const float*)d_in[6];
    const float* gr = (const float*)d_in[7];
    float* out = (float*)d_out;
    int* cnt = (int*)d_ws;  // ws is re-poisoned 0xAA each launch -> must zero

    hipMemsetAsync(cnt, 0, sizeof(int), stream);
    alive_count_kernel<<<256, 256, 0, stream>>>(x, cnt);
    dim3 grid(kW / TW, kH / TH, kB);
    nca_fused_kernel<<<grid, 256, 0, stream>>>(x, w1, b1, w2, b2, w3, b3, gr, cnt, out);
}

// Round 3
// 474.474 us; speedup vs baseline: 1.1955x; 1.0043x over previous
//
#include <hip/hip_runtime.h>

namespace {

constexpr int kH = 512, kW = 512, kB = 16, kC = 8;
constexpr int kHW = kH * kW;      // 262144 per-channel plane
constexpr int kBS = kC * kHW;     // 2097152 per-batch stride
constexpr int TW = 64, TH = 4;    // pixel tile per 256-thread block
constexpr int TWP = TW + 2, THP = TH + 2;

// Kernel 1: count alive cells (x[:,3,:,:] > 0.1). One atomic per block.
__global__ __launch_bounds__(256)
void alive_count_kernel(const float* __restrict__ x, int* __restrict__ cnt) {
    __shared__ int sdata[4];
    const int tid = threadIdx.x;
    const int total4 = kB * kHW / 4;          // 1048576 float4s across 16 planes
    int idx = blockIdx.x * 256 + tid;
    const int stride = gridDim.x * 256;
    int local = 0;
    const float4* x4 = (const float4*)x;
    for (int i = idx; i < total4; i += stride) {
        int b = i >> 16;                       // kHW/4 == 65536
        int off = i & 65535;
        float4 v = x4[(size_t)b * (kBS / 4) + (3 * kHW / 4) + off];
        local += (v.x > 0.1f) + (v.y > 0.1f) + (v.z > 0.1f) + (v.w > 0.1f);
    }
    for (int off = 32; off > 0; off >>= 1)
        local += __shfl_down(local, off, 64);
    if ((tid & 63) == 0) sdata[tid >> 6] = local;
    __syncthreads();
    if (tid == 0) atomicAdd(cnt, sdata[0] + sdata[1] + sdata[2] + sdata[3]);
}

// Kernel 2: fused NCA step.
// R3: __launch_bounds__(256, 2) — R2 showed VGPR_Count=40 with ~88 live
// floats/thread (p[24]+h1[32]+h2[32]): compiler was spilling the MLP arrays
// to AGPRs (v_accvgpr VALU traffic ~2.5x'd the instruction count). 2 waves/EU
// allows up to 256 VGPRs so the whole MLP stays in registers; VALU-bound
// kernel needs little occupancy.
__global__ __launch_bounds__(256, 2)
void nca_fused_kernel(const float* __restrict__ x,
                      const float* __restrict__ w1, const float* __restrict__ b1,
                      const float* __restrict__ w2, const float* __restrict__ b2,
                      const float* __restrict__ w3, const float* __restrict__ b3,
                      const float* __restrict__ growth,
                      const int* __restrict__ alive_cnt,
                      float* __restrict__ out) {
    __shared__ float tile[kC][THP][TWP];  // 3168 floats = 12672 B

    const int w0 = blockIdx.x * TW;
    const int h0 = blockIdx.y * TH;
    const int b  = blockIdx.z;
    const int tid = threadIdx.x;
    const float* xb = x + b * kBS;

    constexpr int TILE_N = kC * THP * TWP;  // 3168
    for (int i = tid; i < TILE_N; i += 256) {
        int c  = i / (THP * TWP);
        int r  = i - c * (THP * TWP);
        int hh = r / TWP;
        int ww = r - hh * TWP;
        int gh = h0 + hh - 1;
        int gw = w0 + ww - 1;
        float v = 0.0f;
        if ((unsigned)gh < (unsigned)kH && (unsigned)gw < (unsigned)kW)
            v = xb[c * kHW + gh * kW + gw];
        (&tile[0][0][0])[i] = v;
    }
    __syncthreads();

    const int ww = tid & (TW - 1);
    const int hh = tid >> 6;

    float p[24];
    int nalive = 0;
#pragma unroll
    for (int c = 0; c < kC; ++c) {
        float a00 = tile[c][hh    ][ww], a01 = tile[c][hh    ][ww + 1], a02 = tile[c][hh    ][ww + 2];
        float a10 = tile[c][hh + 1][ww], a11 = tile[c][hh + 1][ww + 1], a12 = tile[c][hh + 1][ww + 2];
        float a20 = tile[c][hh + 2][ww], a21 = tile[c][hh + 2][ww + 1], a22 = tile[c][hh + 2][ww + 2];
        p[c]      = a11;
        p[8 + c]  = (a02 - a00) + 2.0f * (a12 - a10) + (a22 - a20);   // sobel_x
        p[16 + c] = (a20 - a00) + 2.0f * (a21 - a01) + (a22 - a02);   // sobel_y
        if (c == 3) {
            nalive = (a00 > 0.1f) + (a01 > 0.1f) + (a02 > 0.1f)
                   + (a10 > 0.1f) + (a11 > 0.1f) + (a12 > 0.1f)
                   + (a20 > 0.1f) + (a21 > 0.1f) + (a22 > 0.1f);
        }
    }

    float h1[32];
#pragma unroll
    for (int o = 0; o < 32; ++o) {
        float acc = b1[o];
#pragma unroll
        for (int i2 = 0; i2 < 24; ++i2) acc = fmaf(w1[o * 24 + i2], p[i2], acc);
        h1[o] = fmaxf(acc, 0.0f);
    }
    float h2[32];
#pragma unroll
    for (int o = 0; o < 32; ++o) {
        float acc = b2[o];
#pragma unroll
        for (int i2 = 0; i2 < 32; ++i2) acc = fmaf(w2[o * 32 + i2], h1[i2], acc);
        h2[o] = fmaxf(acc, 0.0f);
    }
    float d[8];
#pragma unroll
    for (int o = 0; o < 8; ++o) {
        float acc = b3[o];
#pragma unroll
        for (int i2 = 0; i2 < 32; ++i2) acc = fmaf(w3[o * 32 + i2], h2[i2], acc);
        d[o] = acc;
    }

    const float g = growth[0];  // GROWTH_BOOST == 1.0
    const float ratio = (float)(*alive_cnt) * (1.0f / 4194304.0f);
    const float boost = (ratio < 0.2f && nalive > 0) ? 0.2f : 0.0f;

    float* ob = out + b * kBS + (h0 + hh) * kW + (w0 + ww);
#pragma unroll
    for (int c = 0; c < kC; ++c) {
        float v = p[c] + d[c] * g + ((c == 3) ? boost : 0.0f);
        const float lo = (c == 3) ? 0.0f : -1.0f;
        v = fminf(fmaxf(v, lo), 1.0f);
        ob[c * kHW] = v;
    }
}

}  // namespace

extern "C" void kernel_launch(void* const* d_in, const int* in_sizes, int n_in,
                              void* d_out, int out_size, void* d_ws, size_t ws_size,
                              hipStream_t stream) {
    const float* x  = (const float*)d_in[0];
    const float* w1 = (const float*)d_in[1];
    const float* b1 = (const float*)d_in[2];
    const float* w2 = (const float*)d_in[3];
    const float* b2 = (const float*)d_in[4];
    const float* w3 = (const float*)d_in[5];
    const float* b3 = (const float*)d_in[6];
    const float* gr = (const float*)d_in[7];
    float* out = (float*)d_out;
    int* cnt = (int*)d_ws;  // ws is re-poisoned 0xAA each launch -> must zero

    hipMemsetAsync(cnt, 0, sizeof(int), stream);
    alive_count_kernel<<<256, 256, 0, stream>>>(x, cnt);
    dim3 grid(kW / TW, kH / TH, kB);
    nca_fused_kernel<<<grid, 256, 0, stream>>>(x, w1, b1, w2, b2, w3, b3, gr, cnt, out);
}